// Round 3
// baseline (4765.220 us; speedup 1.0000x reference)
//
#include <hip/hip_runtime.h>
#include <hip/hip_bf16.h>
#include <hip/hip_cooperative_groups.h>

namespace cg = cooperative_groups;

typedef unsigned short u16;
typedef unsigned int u32;
typedef __attribute__((ext_vector_type(8))) short short8;
typedef __attribute__((ext_vector_type(4))) float floatx4;

#define NT 128
#define NB 256
#define NC 512
#define HID 256
#define EMB 128
#define NCLS 37
#define NSTEPS 25
#define POSEC 256
#define RNN_IN 1472

__device__ __forceinline__ float b2f(u16 u) {
    union { float f; u32 i; } v; v.i = ((u32)u) << 16; return v.f;
}
__device__ __forceinline__ u16 f2b(float f) {
    union { float f; u32 i; } v; v.f = f;
    u32 x = v.i;
    return (u16)((x + 0x7fffu + ((x >> 16) & 1u)) >> 16);  // RNE
}
__device__ __forceinline__ float sigm(float x) { return 1.f / (1.f + __expf(-x)); }

// fast tanh: (1 - e^{-2|x|}) / (1 + e^{-2|x|}) with sign restore
__device__ __forceinline__ float ftanh(float x) {
    float t = __expf(-2.f * fabsf(x));
    float r = (1.f - t) * __builtin_amdgcn_rcpf(1.f + t);
    return copysignf(r, x);
}

// dtype-polymorphic loads
__device__ __forceinline__ float ldf(const float* p, size_t i) { return p[i]; }
__device__ __forceinline__ float ldf(const u16* p, size_t i) { return b2f(p[i]); }

__device__ __forceinline__ short8 ld8(const u16* p) { return *(const short8*)p; }
__device__ __forceinline__ short8 ld8(const float* p) {
    float4 a = *(const float4*)p; float4 b = *(const float4*)(p + 4);
    short8 r;
    r[0] = (short)f2b(a.x); r[1] = (short)f2b(a.y); r[2] = (short)f2b(a.z); r[3] = (short)f2b(a.w);
    r[4] = (short)f2b(b.x); r[5] = (short)f2b(b.y); r[6] = (short)f2b(b.z); r[7] = (short)f2b(b.w);
    return r;
}
__device__ __forceinline__ float4 ld4(const float* p) { return *(const float4*)p; }
__device__ __forceinline__ float4 ld4(const u16* p) {
    ushort4 v = *(const ushort4*)p;
    return make_float4(b2f(v.x), b2f(v.y), b2f(v.z), b2f(v.w));
}

// ---------------- dtype probe (1 = bf16, 0 = f32)
__global__ void probe_kernel(const void* score_w, int* flag) {
    __shared__ float red[128];
    int tid = threadIdx.x;
    const u16* p = (const u16*)score_w;
    float v = fabsf(b2f(p[tid]));
    v = (v == v && v < 1e6f) ? v : 1e6f;
    red[tid] = v;
    __syncthreads();
    for (int s2 = 64; s2 > 0; s2 >>= 1) {
        if (tid < s2) red[tid] += red[tid + s2];
        __syncthreads();
    }
    if (tid == 0) flag[0] = (red[0] < 1000.f) ? 1 : 0;
}

// ---------------- canonicalize GRU weights to bf16 + pack h2h_w transposed
// h2h_wT packed: out[(c>>1)*512 + 2*j + (c&1)] = h2h_w[j][c]
__global__ void conv_kernel(const void* w_ih, const void* w_hh, const void* h2h_w,
                            u16* out_ih, u16* out_hh, u16* out_h2h, const int* flagp) {
    int f = *flagp;
    int idx = blockIdx.x * blockDim.x + threadIdx.x;
    int stride = gridDim.x * blockDim.x;
    const int n_ih = 768 * RNN_IN, n_hh = 768 * HID, n_h2h = HID * HID;
    if (f) {
        const u16* a = (const u16*)w_ih; const u16* b = (const u16*)w_hh;
        const u16* c = (const u16*)h2h_w;
        for (int i = idx; i < n_ih; i += stride) out_ih[i] = a[i];
        for (int i = idx; i < n_hh; i += stride) out_hh[i] = b[i];
        for (int i = idx; i < n_h2h; i += stride) {
            int j = i >> 8, cc = i & 255;
            out_h2h[(cc >> 1) * 512 + (j << 1) + (cc & 1)] = c[i];
        }
    } else {
        const float* a = (const float*)w_ih; const float* b = (const float*)w_hh;
        const float* c = (const float*)h2h_w;
        for (int i = idx; i < n_ih; i += stride) out_ih[i] = f2b(a[i]);
        for (int i = idx; i < n_hh; i += stride) out_hh[i] = f2b(b[i]);
        for (int i = idx; i < n_h2h; i += stride) {
            int j = i >> 8, cc = i & 255;
            out_h2h[(cc >> 1) * 512 + (j << 1) + (cc & 1)] = f2b(c[i]);
        }
    }
}

// ---------------- pose (b,p,1,t) -> bf16 pt[b][p][t]  (read 25x, convert once)
template <typename T>
__device__ void pconv_body(const T* pose, u16* pt) {
    size_t n = (size_t)NB * POSEC * NT;
    size_t i = ((size_t)blockIdx.x * blockDim.x + threadIdx.x) * 4;
    size_t stride = (size_t)gridDim.x * blockDim.x * 4;
    for (; i < n; i += stride) {
        float4 v = ld4(pose + i);
        ushort4 o;
        o.x = f2b(v.x); o.y = f2b(v.y); o.z = f2b(v.z); o.w = f2b(v.w);
        *(ushort4*)(pt + i) = o;
    }
}
__global__ __launch_bounds__(256) void pconv_kernel(const void* pose, u16* pt, const int* flagp) {
    if (*flagp) pconv_body((const u16*)pose, pt);
    else        pconv_body((const float*)pose, pt);
}

// ---------------- transpose feats (t,b,c) -> ft[b][c][t]
template <typename T>
__device__ void trans_body(const T* feats, u16* ft) {
    int b = blockIdx.x, t0 = blockIdx.y * 8;
    #pragma unroll
    for (int half = 0; half < 2; half++) {
        int c = threadIdx.x + half * 256;
        short8 v;
        #pragma unroll
        for (int j = 0; j < 8; j++)
            v[j] = (short)f2b(ldf(feats, ((size_t)(t0 + j) * NB + b) * NC + c));
        *(short8*)(ft + ((size_t)b * NC + c) * NT + t0) = v;
    }
}
__global__ __launch_bounds__(256) void trans_kernel(const void* feats, u16* ft, const int* flagp) {
    if (*flagp) trans_body((const u16*)feats, ft);
    else        trans_body((const float*)feats, ft);
}

// ---------------- feats_proj: LDS-tiled MFMA GEMM, 128x128 tile, BK=32
template <typename T>
__device__ void fp_body(const T* feats, const T* i2h_w, u16* fp) {
    __shared__ u16 As[128][40];   // +8 pad
    __shared__ u16 Bs[128][40];
    const int tid = threadIdx.x;
    const int w = tid >> 6, lane = tid & 63;
    const int m0 = blockIdx.x * 128, n0 = blockIdx.y * 128;
    const int lr = lane & 15, kq = (lane >> 4) * 8;
    const int srow = tid >> 1, schunk = (tid & 1) * 16;

    floatx4 acc[2][8];
    #pragma unroll
    for (int i = 0; i < 2; i++)
        #pragma unroll
        for (int nt = 0; nt < 8; nt++) acc[i][nt] = (floatx4){0.f, 0.f, 0.f, 0.f};

    for (int kk = 0; kk < NC; kk += 32) {
        short8 av0 = ld8(feats + (size_t)(m0 + srow) * NC + kk + schunk);
        short8 av1 = ld8(feats + (size_t)(m0 + srow) * NC + kk + schunk + 8);
        short8 bv0 = ld8(i2h_w + (size_t)(n0 + srow) * NC + kk + schunk);
        short8 bv1 = ld8(i2h_w + (size_t)(n0 + srow) * NC + kk + schunk + 8);
        __syncthreads();
        *(short8*)&As[srow][schunk] = av0;
        *(short8*)&As[srow][schunk + 8] = av1;
        *(short8*)&Bs[srow][schunk] = bv0;
        *(short8*)&Bs[srow][schunk + 8] = bv1;
        __syncthreads();
        short8 a0 = *(const short8*)&As[w * 32 + lr][kq];
        short8 a1 = *(const short8*)&As[w * 32 + 16 + lr][kq];
        #pragma unroll
        for (int nt = 0; nt < 8; nt++) {
            short8 bf = *(const short8*)&Bs[nt * 16 + lr][kq];
            acc[0][nt] = __builtin_amdgcn_mfma_f32_16x16x32_bf16(a0, bf, acc[0][nt], 0, 0, 0);
            acc[1][nt] = __builtin_amdgcn_mfma_f32_16x16x32_bf16(a1, bf, acc[1][nt], 0, 0, 0);
        }
    }

    int rbase = (lane >> 4) * 4, col = lane & 15;
    #pragma unroll
    for (int i = 0; i < 2; i++)
        #pragma unroll
        for (int nt = 0; nt < 8; nt++)
            #pragma unroll
            for (int r = 0; r < 4; r++) {
                int m = m0 + w * 32 + i * 16 + rbase + r;
                int t = m >> 8, b = m & 255;
                fp[((size_t)b * NT + t) * HID + n0 + nt * 16 + col] = f2b(acc[i][nt][r]);
            }
}
__global__ __launch_bounds__(256) void fp_kernel(const void* feats, const void* i2h_w,
                                                 u16* fp, const int* flagp) {
    if (*flagp) fp_body((const u16*)feats, (const u16*)i2h_w, fp);
    else        fp_body((const float*)feats, (const float*)i2h_w, fp);
}

// ---------------- ROI-align 2x2
template <typename T>
__device__ __forceinline__ void do_crop(
    const T* __restrict__ f, int C, int H, int W,
    float x1, float y1, float x2, float y2,
    u16* __restrict__ xrow, int off, int tid)
{
    int n = C * 4;
    if (tid >= n) return;
    float bw = fmaxf(x2 - x1, 1.f) * 0.5f;
    float bh = fmaxf(y2 - y1, 1.f) * 0.5f;
    int c = tid >> 2, iy = (tid >> 1) & 1, ix = tid & 1;
    float yy = y1 + (0.5f + (float)iy) * bh;
    float xx = x1 + (0.5f + (float)ix) * bw;
    bool valid = (yy >= -1.f) && (yy <= (float)H) && (xx <= (float)W) && (xx >= -1.f);
    float y = fminf(fmaxf(yy, 0.f), (float)(H - 1));
    float x = fminf(fmaxf(xx, 0.f), (float)(W - 1));
    float y0f = floorf(y), x0f = floorf(x);
    int y0 = (int)y0f, x0 = (int)x0f;
    int y1i = min(y0 + 1, H - 1), x1i = min(x0 + 1, W - 1);
    float ly = y - y0f, lx = x - x0f, hy = 1.f - ly, hx = 1.f - lx;
    size_t base = (size_t)c * H * W;
    float v = ldf(f, base + y0 * W + x0) * hy * hx + ldf(f, base + y0 * W + x1i) * hy * lx
            + ldf(f, base + y1i * W + x0) * ly * hx + ldf(f, base + y1i * W + x1i) * ly * lx;
    xrow[off + tid] = f2b(valid ? v : 0.f);
}

// ---------------- attn phase (one block per b; hp GEMV fused, prefetch-ordered)
template <typename T>
__device__ __forceinline__ void attn_step(
    int s, int b, int tid,
    const u16* pt, const T* pyr0, const T* pyr1, const T* pyr2,
    const int* text, const T* h2h_b, const T* score_w, const T* pose_w,
    const T* pose_b, const T* char_emb, const u16* h2h_wT,
    const u16* ft, const u16* fp, const u16* h_cur, u16* xout, float* smem)
{
    float* h_s    = smem;          // 256
    float* hp_s   = smem + 256;    // 264 (skewed)
    float* sw_s   = smem + 520;    // 264 (skewed)
    float* ep_s   = smem + 784;    // 512
    float* pp_s   = smem + 1296;   // 512
    float* e_s    = smem + 1808;   // 128 (alpha)
    float* ctx_s  = smem + 1936;   // 768
    float* coord_s= smem + 2704;   // 4

    // ---- prologue: issue loads in the order they will be consumed.
    // vmcnt is FIFO: waiting on the hp weights (issued before fp/ft) never
    // drains the fp/ft streams.
    float hv = 0.f, swv = 0.f;
    if (tid < 256) hv = b2f(h_cur[b * HID + tid]);
    else           swv = ldf(score_w, tid - 256);

    // hp weights: thread (j = tid&255, half = tid>>8), coalesced u32 (2 k each)
    u32 wv[64];
    {
        const u16* wp = h2h_wT + 2 * (tid & 255) + (size_t)(tid >> 8) * 64 * 512;
        #pragma unroll
        for (int i = 0; i < 64; i++) wv[i] = *(const u32*)(wp + i * 512);
    }

    // e-phase fp slice: thread (t = tid>>2, q = tid&3) covers h in [q*64, q*64+64)
    const int t_e = tid >> 2, q_e = tid & 3;
    const u16* fpr = fp + ((size_t)b * NT + t_e) * HID + q_e * 64;
    short8 fpv[8];
    #pragma unroll
    for (int i = 0; i < 8; i++) fpv[i] = *(const short8*)(fpr + 8 * i);

    // ctx-feats slice: channel c = tid, all 128 t
    const u16* ftr = ft + ((size_t)b * NC + tid) * NT;
    short8 ftv[16];
    #pragma unroll
    for (int i = 0; i < 16; i++) ftv[i] = *(const short8*)(ftr + 8 * i);

    int tgt = 0;
    if (s > 0) tgt = text[b * NSTEPS + (s - 1)] + 1;
    float embv = 0.f;
    if (tid >= 256 && tid < 256 + EMB)
        embv = ldf(char_emb, (size_t)tgt * EMB + (tid - 256));

    // ---- stage h + sw into LDS
    if (tid < 256) h_s[tid] = hv;
    else { int k = tid - 256; sw_s[k + (k >> 5)] = swv; }
    __syncthreads();

    // ---- hp GEMV (weights already in regs; h_s reads are wave-broadcast)
    {
        int base = (tid >> 8) * 128;
        float acc = 0.f;
        #pragma unroll
        for (int i = 0; i < 64; i++) {
            u32 w2 = wv[i];
            acc += h_s[base + 2 * i] * b2f((u16)w2)
                 + h_s[base + 2 * i + 1] * b2f((u16)(w2 >> 16));
        }
        ep_s[tid] = acc;
    }
    __syncthreads();
    if (tid < 256) hp_s[tid + (tid >> 5)] = ep_s[tid] + ep_s[tid + 256] + ldf(h2h_b, tid);
    __syncthreads();

    // ---- e partial: acc over 64 h
    {
        float acc = 0.f;
        #pragma unroll
        for (int i = 0; i < 8; i++) {
            short8 v = fpv[i];
            #pragma unroll
            for (int j = 0; j < 8; j++) {
                int h = q_e * 64 + i * 8 + j;
                int ki = h + (h >> 5);
                acc += ftanh(b2f((u16)v[j]) + hp_s[ki]) * sw_s[ki];
            }
        }
        ep_s[tid] = acc;
    }
    __syncthreads();

    // ---- e-combine + softmax, wave 0 only
    if (tid < 64) {
        float4 a = *(const float4*)&ep_s[4 * tid];
        float4 c = *(const float4*)&ep_s[4 * (tid + 64)];
        float eL = a.x + a.y + a.z + a.w;
        float eH = c.x + c.y + c.z + c.w;
        float m = fmaxf(eL, eH);
        #pragma unroll
        for (int off = 32; off; off >>= 1) m = fmaxf(m, __shfl_xor(m, off));
        float pL = __expf(eL - m), pH = __expf(eH - m);
        float sm = pL + pH;
        #pragma unroll
        for (int off = 32; off; off >>= 1) sm += __shfl_xor(sm, off);
        float inv = 1.f / sm;
        e_s[tid] = pL * inv;
        e_s[tid + 64] = pH * inv;
    }
    __syncthreads();

    u16* xr = xout + (size_t)b * RNN_IN;

    // ---- ctx feats (pure VALU: ftv regs x alpha from LDS broadcast)
    {
        float acc = 0.f;
        #pragma unroll
        for (int i = 0; i < 16; i++) {
            float4 a0 = *(const float4*)&e_s[8 * i];
            float4 a1 = *(const float4*)&e_s[8 * i + 4];
            short8 v = ftv[i];
            acc += a0.x * b2f((u16)v[0]) + a0.y * b2f((u16)v[1])
                 + a0.z * b2f((u16)v[2]) + a0.w * b2f((u16)v[3])
                 + a1.x * b2f((u16)v[4]) + a1.y * b2f((u16)v[5])
                 + a1.z * b2f((u16)v[6]) + a1.w * b2f((u16)v[7]);
        }
        ctx_s[tid] = acc;
        xr[tid] = f2b(acc);
    }
    // ---- ctx pose partial (streamed: L2/L3-hot by now)
    {
        const int p_c = tid & 255, hf = tid >> 8;
        const u16* pr = pt + ((size_t)b * POSEC + p_c) * NT + hf * 64;
        float acc = 0.f;
        #pragma unroll
        for (int i = 0; i < 8; i++) {
            short8 v = *(const short8*)(pr + 8 * i);
            float4 a0 = *(const float4*)&e_s[hf * 64 + 8 * i];
            float4 a1 = *(const float4*)&e_s[hf * 64 + 8 * i + 4];
            acc += a0.x * b2f((u16)v[0]) + a0.y * b2f((u16)v[1])
                 + a0.z * b2f((u16)v[2]) + a0.w * b2f((u16)v[3])
                 + a1.x * b2f((u16)v[4]) + a1.y * b2f((u16)v[5])
                 + a1.z * b2f((u16)v[6]) + a1.w * b2f((u16)v[7]);
        }
        pp_s[tid] = acc;
    }
    // emb write (independent)
    if (tid >= 256 && tid < 256 + EMB) xr[768 + (tid - 256)] = f2b(embv);
    __syncthreads();
    if (tid < 256) {
        float v = pp_s[tid] + pp_s[tid + 256];
        ctx_s[512 + tid] = v;
        xr[512 + tid] = f2b(v);
    }
    __syncthreads();

    // ---- coord = sigmoid(ctx @ pose_w.T + pose_b)  (streamed weights, L2-hot)
    if (tid < 256) {
        int j = tid >> 6, lane = tid & 63;
        float acc = 0.f;
        #pragma unroll
        for (int k = 0; k < 12; k++)
            acc += ctx_s[lane + k * 64] * ldf(pose_w, (size_t)j * 768 + k * 64 + lane);
        #pragma unroll
        for (int off = 32; off; off >>= 1) acc += __shfl_down(acc, off);
        if (lane == 0) coord_s[j] = sigm(acc + ldf(pose_b, j));
    }
    __syncthreads();

    float c0 = coord_s[0], c1 = coord_s[1], c2 = coord_s[2], c3 = coord_s[3];
    // crops in disjoint thread ranges (<=2 serial crops per thread)
    if (tid < 64) {
        do_crop(pyr0, 16, 16, 128, c0 * 16.f,  c1 * 128.f,    c2 * 16.f,  c3 * 128.f,    xr, 896,  tid);
        do_crop(pyr2, 64, 4,  65,  c0 * 512.f, c1 * 532480.f, c2 * 512.f, c3 * 532480.f, xr, 1216, tid + 192);
    } else if (tid < 320) {
        do_crop(pyr1, 64, 8,  64,  c0 * 128.f, c1 * 8192.f,   c2 * 128.f, c3 * 8192.f,   xr, 960,  tid - 64);
    } else {
        do_crop(pyr2, 64, 4,  65,  c0 * 512.f, c1 * 532480.f, c2 * 512.f, c3 * 532480.f, xr, 1216, tid - 320);
    }
}

// ---------------- GRU phase: block bid -> (jt = bid&15, bt = bid>>4)
template <typename T>
__device__ __forceinline__ void gru_step(
    int bid, int tid, const u16* x, const u16* h_prev, u16* h_new,
    const u16* w_ih, const u16* w_hh, const T* b_ih, const T* b_hh, float* red)
{
    const int jt = bid & 15, bt = bid >> 4;
    const int w = tid >> 6, lane = tid & 63;
    const int lr = lane & 15;
    const int kq = (lane >> 4) * 8;
    const int arow = bt * 16 + lr;

    floatx4 acc_r = {0.f,0.f,0.f,0.f}, acc_z = acc_r, acc_in = acc_r, acc_hn = acc_r;

    for (int kc = w; kc < RNN_IN / 32; kc += 8) {
        int k0 = kc * 32 + kq;
        short8 a = *(const short8*)(x + (size_t)arow * RNN_IN + k0);
        short8 b0 = *(const short8*)(w_ih + (size_t)(0 * HID + jt * 16 + lr) * RNN_IN + k0);
        short8 b1 = *(const short8*)(w_ih + (size_t)(1 * HID + jt * 16 + lr) * RNN_IN + k0);
        short8 b2 = *(const short8*)(w_ih + (size_t)(2 * HID + jt * 16 + lr) * RNN_IN + k0);
        acc_r  = __builtin_amdgcn_mfma_f32_16x16x32_bf16(a, b0, acc_r, 0, 0, 0);
        acc_z  = __builtin_amdgcn_mfma_f32_16x16x32_bf16(a, b1, acc_z, 0, 0, 0);
        acc_in = __builtin_amdgcn_mfma_f32_16x16x32_bf16(a, b2, acc_in, 0, 0, 0);
    }
    for (int kc = w; kc < HID / 32; kc += 8) {
        int k0 = kc * 32 + kq;
        short8 a = *(const short8*)(h_prev + (size_t)arow * HID + k0);
        short8 b0 = *(const short8*)(w_hh + (size_t)(0 * HID + jt * 16 + lr) * HID + k0);
        short8 b1 = *(const short8*)(w_hh + (size_t)(1 * HID + jt * 16 + lr) * HID + k0);
        short8 b2 = *(const short8*)(w_hh + (size_t)(2 * HID + jt * 16 + lr) * HID + k0);
        acc_r  = __builtin_amdgcn_mfma_f32_16x16x32_bf16(a, b0, acc_r, 0, 0, 0);
        acc_z  = __builtin_amdgcn_mfma_f32_16x16x32_bf16(a, b1, acc_z, 0, 0, 0);
        acc_hn = __builtin_amdgcn_mfma_f32_16x16x32_bf16(a, b2, acc_hn, 0, 0, 0);
    }

    int jcol = lane & 15, rb = (lane >> 4) * 4;
    #pragma unroll
    for (int r = 0; r < 4; r++) {
        red[((w * 4 + 0) * 16 + jcol) * 17 + rb + r] = acc_r[r];
        red[((w * 4 + 1) * 16 + jcol) * 17 + rb + r] = acc_z[r];
        red[((w * 4 + 2) * 16 + jcol) * 17 + rb + r] = acc_in[r];
        red[((w * 4 + 3) * 16 + jcol) * 17 + rb + r] = acc_hn[r];
    }
    __syncthreads();

    if (tid < 256) {
        int jj = tid >> 4, bl = tid & 15;
        float sr = 0, sz = 0, sin_ = 0, shn = 0;
        #pragma unroll
        for (int w2 = 0; w2 < 8; w2++) {
            sr   += red[((w2 * 4 + 0) * 16 + jj) * 17 + bl];
            sz   += red[((w2 * 4 + 1) * 16 + jj) * 17 + bl];
            sin_ += red[((w2 * 4 + 2) * 16 + jj) * 17 + bl];
            shn  += red[((w2 * 4 + 3) * 16 + jj) * 17 + bl];
        }
        int j = jt * 16 + jj, b = bt * 16 + bl;
        float r  = sigm(sr + ldf(b_ih, j) + ldf(b_hh, j));
        float zz = sigm(sz + ldf(b_ih, j + 256) + ldf(b_hh, j + 256));
        float n  = ftanh(sin_ + ldf(b_ih, j + 512) + r * (shn + ldf(b_hh, j + 512)));
        float hp = b2f(h_prev[(size_t)b * HID + j]);
        h_new[(size_t)b * HID + j] = f2b((1.f - zz) * n + zz * hp);
    }
    __syncthreads();
}

// ---------------- cooperative loop kernel: 25 x (attn -> sync -> gru -> sync)
template <typename T>
__device__ void run_loop(
    const u16* pt, const T* pyr0, const T* pyr1, const T* pyr2,
    const int* text, const T* h2h_b, const T* score_w, const T* pose_w,
    const T* pose_b, const T* char_emb, const u16* h2h_wT,
    const u16* ft, const u16* fp, u16* hs, u16* x,
    const u16* w_ih, const u16* w_hh, const T* b_ih, const T* b_hh,
    float* smem, cg::grid_group& grid)
{
    const int bid = blockIdx.x, tid = threadIdx.x;
    for (int s = 0; s < NSTEPS; s++) {
        attn_step<T>(s, bid, tid, pt, pyr0, pyr1, pyr2, text, h2h_b, score_w,
                     pose_w, pose_b, char_emb, h2h_wT, ft, fp,
                     hs + (size_t)s * NB * HID, x, smem);
        __threadfence();
        grid.sync();
        gru_step<T>(bid, tid, x, hs + (size_t)s * NB * HID,
                    hs + (size_t)(s + 1) * NB * HID,
                    w_ih, w_hh, b_ih, b_hh, smem);
        __threadfence();
        grid.sync();
    }
}

__global__ __launch_bounds__(512, 2) void coop_kernel(
    const u16* pt, const void* pyr0, const void* pyr1, const void* pyr2,
    const int* text, const void* h2h_b, const void* score_w, const void* pose_w,
    const void* pose_b, const void* char_emb, const u16* h2h_wT,
    const u16* ft, const u16* fp, u16* hs, u16* x,
    const u16* w_ih, const u16* w_hh, const void* b_ih, const void* b_hh,
    const int* flagp)
{
    __shared__ __align__(16) float smem[8704];   // 34816 B: max(gru red, attn)
    cg::grid_group grid = cg::this_grid();
    if (*flagp)
        run_loop<u16>(pt, (const u16*)pyr0, (const u16*)pyr1, (const u16*)pyr2,
                      text, (const u16*)h2h_b, (const u16*)score_w,
                      (const u16*)pose_w, (const u16*)pose_b, (const u16*)char_emb,
                      h2h_wT, ft, fp, hs, x, w_ih, w_hh,
                      (const u16*)b_ih, (const u16*)b_hh, smem, grid);
    else
        run_loop<float>(pt, (const float*)pyr0, (const float*)pyr1, (const float*)pyr2,
                        text, (const float*)h2h_b, (const float*)score_w,
                        (const float*)pose_w, (const float*)pose_b, (const float*)char_emb,
                        h2h_wT, ft, fp, hs, x, w_ih, w_hh,
                        (const float*)b_ih, (const float*)b_hh, smem, grid);
}

// ---------------- final classifier
template <typename T>
__device__ void gen_body(const u16* hs, const T* gen_w, const T* gen_b, void* out) {
    int rowid = blockIdx.x;
    int b = rowid / NSTEPS, s = rowid % NSTEPS;
    const u16* h = hs + ((size_t)(s + 1) * NB + b) * HID;
    extern __shared__ float hsd[];
    int tid = threadIdx.x;
    for (int i = tid; i < HID; i += 64) hsd[i] = b2f(h[i]);
    __syncthreads();
    if (tid < NCLS) {
        float acc = ldf(gen_b, tid);
        const T* wr = gen_w + (size_t)tid * HID;
        #pragma unroll 4
        for (int k4 = 0; k4 < HID / 4; k4++) {
            float4 wv = ld4(wr + 4 * k4);
            acc += hsd[4 * k4 + 0] * wv.x + hsd[4 * k4 + 1] * wv.y
                 + hsd[4 * k4 + 2] * wv.z + hsd[4 * k4 + 3] * wv.w;
        }
        size_t o = (size_t)rowid * NCLS + tid;
        if (sizeof(T) == 2) ((u16*)out)[o] = f2b(acc);
        else                ((float*)out)[o] = acc;
    }
}
__global__ __launch_bounds__(64) void gen_kernel(
    const u16* hs, const void* gen_w, const void* gen_b, void* out, const int* flagp)
{
    if (*flagp) gen_body(hs, (const u16*)gen_w, (const u16*)gen_b, out);
    else        gen_body(hs, (const float*)gen_w, (const float*)gen_b, out);
}

extern "C" void kernel_launch(void* const* d_in, const int* in_sizes, int n_in,
                              void* d_out, int out_size, void* d_ws, size_t ws_size,
                              hipStream_t stream) {
    (void)in_sizes; (void)n_in; (void)out_size;
    const int* text = (const int*)d_in[6];

    char* ws = (char*)d_ws;
    size_t off = 256;
    int* flag = (int*)ws;
    u16* fp = (u16*)(ws + off); off += (size_t)NB * NT * HID * 2;        // 16.78 MB
    u16* ft = (u16*)(ws + off); off += (size_t)NB * NC * NT * 2;         // 33.55 MB
    u16* hs     = (u16*)(ws + off); off += 3407872;
    u16* x      = (u16*)(ws + off); off += 753664;
    u16* wih_c  = (u16*)(ws + off); off += 2260992;
    u16* whh_c  = (u16*)(ws + off); off += 393216;
    u16* h2h_wT = (u16*)(ws + off); off += 131072;
    u16* pt     = (u16*)(ws + off); off += (size_t)NB * POSEC * NT * 2;  // 16.78 MB

    probe_kernel<<<1, 128, 0, stream>>>(d_in[10], flag);
    conv_kernel<<<512, 256, 0, stream>>>(d_in[13], d_in[14], d_in[8],
                                         wih_c, whh_c, h2h_wT, flag);
    hipMemsetAsync(hs, 0, (size_t)NB * HID * 2, stream);  // h0 = 0
    fp_kernel<<<dim3(256, 2), 256, 0, stream>>>(d_in[0], d_in[7], fp, flag);
    trans_kernel<<<dim3(NB, NT / 8), 256, 0, stream>>>(d_in[0], ft, flag);
    pconv_kernel<<<2048, 256, 0, stream>>>(d_in[1], pt, flag);

    // cooperative loop: 256 blocks (1/CU) x 512 threads
    {
        const u16* a_pt = pt;
        const void* a_p0 = d_in[2];
        const void* a_p1 = d_in[3];
        const void* a_p2 = d_in[4];
        const int* a_text = text;
        const void* a_h2hb = d_in[9];
        const void* a_sw = d_in[10];
        const void* a_pw = d_in[11];
        const void* a_pb = d_in[12];
        const void* a_ce = d_in[17];
        const u16* a_h2hwT = h2h_wT;
        const u16* a_ft = ft;
        const u16* a_fp = fp;
        u16* a_hs = hs;
        u16* a_x = x;
        const u16* a_wih = wih_c;
        const u16* a_whh = whh_c;
        const void* a_bih = d_in[15];
        const void* a_bhh = d_in[16];
        const int* a_flag = flag;
        void* kargs[20] = {
            (void*)&a_pt, (void*)&a_p0, (void*)&a_p1, (void*)&a_p2,
            (void*)&a_text, (void*)&a_h2hb, (void*)&a_sw, (void*)&a_pw,
            (void*)&a_pb, (void*)&a_ce, (void*)&a_h2hwT, (void*)&a_ft,
            (void*)&a_fp, (void*)&a_hs, (void*)&a_x, (void*)&a_wih,
            (void*)&a_whh, (void*)&a_bih, (void*)&a_bhh, (void*)&a_flag
        };
        hipLaunchCooperativeKernel((void*)coop_kernel, dim3(NB), dim3(512),
                                   kargs, 0, stream);
    }

    gen_kernel<<<NB * NSTEPS, 64, 1024, stream>>>(hs, d_in[18], d_in[19], d_out, flag);
}

// Round 4
// 1041.711 us; speedup vs baseline: 4.5744x; 4.5744x over previous
//
#include <hip/hip_runtime.h>
#include <hip/hip_bf16.h>

typedef unsigned short u16;
typedef unsigned int u32;
typedef __attribute__((ext_vector_type(8))) short short8;
typedef __attribute__((ext_vector_type(4))) float floatx4;

#define NT 128
#define NB 256
#define NC 512
#define HID 256
#define EMB 128
#define NCLS 37
#define NSTEPS 25
#define POSEC 256
#define RNN_IN 1472

__device__ __forceinline__ float b2f(u16 u) {
    union { float f; u32 i; } v; v.i = ((u32)u) << 16; return v.f;
}
__device__ __forceinline__ u16 f2b(float f) {
    union { float f; u32 i; } v; v.f = f;
    u32 x = v.i;
    return (u16)((x + 0x7fffu + ((x >> 16) & 1u)) >> 16);  // RNE
}
__device__ __forceinline__ float sigm(float x) { return 1.f / (1.f + __expf(-x)); }

// fast tanh: (1 - e^{-2|x|}) / (1 + e^{-2|x|}) with sign restore
__device__ __forceinline__ float ftanh(float x) {
    float t = __expf(-2.f * fabsf(x));
    float r = (1.f - t) * __builtin_amdgcn_rcpf(1.f + t);
    return copysignf(r, x);
}

// dtype-polymorphic loads
__device__ __forceinline__ float ldf(const float* p, size_t i) { return p[i]; }
__device__ __forceinline__ float ldf(const u16* p, size_t i) { return b2f(p[i]); }

__device__ __forceinline__ short8 ld8(const u16* p) { return *(const short8*)p; }
__device__ __forceinline__ short8 ld8(const float* p) {
    float4 a = *(const float4*)p; float4 b = *(const float4*)(p + 4);
    short8 r;
    r[0] = (short)f2b(a.x); r[1] = (short)f2b(a.y); r[2] = (short)f2b(a.z); r[3] = (short)f2b(a.w);
    r[4] = (short)f2b(b.x); r[5] = (short)f2b(b.y); r[6] = (short)f2b(b.z); r[7] = (short)f2b(b.w);
    return r;
}
__device__ __forceinline__ float4 ld4(const float* p) { return *(const float4*)p; }
__device__ __forceinline__ float4 ld4(const u16* p) {
    ushort4 v = *(const ushort4*)p;
    return make_float4(b2f(v.x), b2f(v.y), b2f(v.z), b2f(v.w));
}

// ---------------- dtype probe (1 = bf16, 0 = f32)
__global__ void probe_kernel(const void* score_w, int* flag) {
    __shared__ float red[128];
    int tid = threadIdx.x;
    const u16* p = (const u16*)score_w;
    float v = fabsf(b2f(p[tid]));
    v = (v == v && v < 1e6f) ? v : 1e6f;
    red[tid] = v;
    __syncthreads();
    for (int s2 = 64; s2 > 0; s2 >>= 1) {
        if (tid < s2) red[tid] += red[tid + s2];
        __syncthreads();
    }
    if (tid == 0) flag[0] = (red[0] < 1000.f) ? 1 : 0;
}

// ---------------- canonicalize GRU weights to bf16 + pack h2h_w transposed
// h2h_wT packed: out[(c>>1)*512 + 2*j + (c&1)] = h2h_w[j][c]
__global__ void conv_kernel(const void* w_ih, const void* w_hh, const void* h2h_w,
                            u16* out_ih, u16* out_hh, u16* out_h2h, const int* flagp) {
    int f = *flagp;
    int idx = blockIdx.x * blockDim.x + threadIdx.x;
    int stride = gridDim.x * blockDim.x;
    const int n_ih = 768 * RNN_IN, n_hh = 768 * HID, n_h2h = HID * HID;
    if (f) {
        const u16* a = (const u16*)w_ih; const u16* b = (const u16*)w_hh;
        const u16* c = (const u16*)h2h_w;
        for (int i = idx; i < n_ih; i += stride) out_ih[i] = a[i];
        for (int i = idx; i < n_hh; i += stride) out_hh[i] = b[i];
        for (int i = idx; i < n_h2h; i += stride) {
            int j = i >> 8, cc = i & 255;
            out_h2h[(cc >> 1) * 512 + (j << 1) + (cc & 1)] = c[i];
        }
    } else {
        const float* a = (const float*)w_ih; const float* b = (const float*)w_hh;
        const float* c = (const float*)h2h_w;
        for (int i = idx; i < n_ih; i += stride) out_ih[i] = f2b(a[i]);
        for (int i = idx; i < n_hh; i += stride) out_hh[i] = f2b(b[i]);
        for (int i = idx; i < n_h2h; i += stride) {
            int j = i >> 8, cc = i & 255;
            out_h2h[(cc >> 1) * 512 + (j << 1) + (cc & 1)] = f2b(c[i]);
        }
    }
}

// ---------------- pose (b,p,1,t) -> bf16 pt[b][p][t]  (read 25x, convert once)
template <typename T>
__device__ void pconv_body(const T* pose, u16* pt) {
    size_t n = (size_t)NB * POSEC * NT;
    size_t i = ((size_t)blockIdx.x * blockDim.x + threadIdx.x) * 4;
    size_t stride = (size_t)gridDim.x * blockDim.x * 4;
    for (; i < n; i += stride) {
        float4 v = ld4(pose + i);
        ushort4 o;
        o.x = f2b(v.x); o.y = f2b(v.y); o.z = f2b(v.z); o.w = f2b(v.w);
        *(ushort4*)(pt + i) = o;
    }
}
__global__ __launch_bounds__(256) void pconv_kernel(const void* pose, u16* pt, const int* flagp) {
    if (*flagp) pconv_body((const u16*)pose, pt);
    else        pconv_body((const float*)pose, pt);
}

// ---------------- transpose feats (t,b,c) -> ft[b][c][t]
template <typename T>
__device__ void trans_body(const T* feats, u16* ft) {
    int b = blockIdx.x, t0 = blockIdx.y * 8;
    #pragma unroll
    for (int half = 0; half < 2; half++) {
        int c = threadIdx.x + half * 256;
        short8 v;
        #pragma unroll
        for (int j = 0; j < 8; j++)
            v[j] = (short)f2b(ldf(feats, ((size_t)(t0 + j) * NB + b) * NC + c));
        *(short8*)(ft + ((size_t)b * NC + c) * NT + t0) = v;
    }
}
__global__ __launch_bounds__(256) void trans_kernel(const void* feats, u16* ft, const int* flagp) {
    if (*flagp) trans_body((const u16*)feats, ft);
    else        trans_body((const float*)feats, ft);
}

// ---------------- feats_proj: LDS-tiled MFMA GEMM, 128x128 tile, BK=32
template <typename T>
__device__ void fp_body(const T* feats, const T* i2h_w, u16* fp) {
    __shared__ u16 As[128][40];   // +8 pad
    __shared__ u16 Bs[128][40];
    const int tid = threadIdx.x;
    const int w = tid >> 6, lane = tid & 63;
    const int m0 = blockIdx.x * 128, n0 = blockIdx.y * 128;
    const int lr = lane & 15, kq = (lane >> 4) * 8;
    const int srow = tid >> 1, schunk = (tid & 1) * 16;

    floatx4 acc[2][8];
    #pragma unroll
    for (int i = 0; i < 2; i++)
        #pragma unroll
        for (int nt = 0; nt < 8; nt++) acc[i][nt] = (floatx4){0.f, 0.f, 0.f, 0.f};

    for (int kk = 0; kk < NC; kk += 32) {
        short8 av0 = ld8(feats + (size_t)(m0 + srow) * NC + kk + schunk);
        short8 av1 = ld8(feats + (size_t)(m0 + srow) * NC + kk + schunk + 8);
        short8 bv0 = ld8(i2h_w + (size_t)(n0 + srow) * NC + kk + schunk);
        short8 bv1 = ld8(i2h_w + (size_t)(n0 + srow) * NC + kk + schunk + 8);
        __syncthreads();
        *(short8*)&As[srow][schunk] = av0;
        *(short8*)&As[srow][schunk + 8] = av1;
        *(short8*)&Bs[srow][schunk] = bv0;
        *(short8*)&Bs[srow][schunk + 8] = bv1;
        __syncthreads();
        short8 a0 = *(const short8*)&As[w * 32 + lr][kq];
        short8 a1 = *(const short8*)&As[w * 32 + 16 + lr][kq];
        #pragma unroll
        for (int nt = 0; nt < 8; nt++) {
            short8 bf = *(const short8*)&Bs[nt * 16 + lr][kq];
            acc[0][nt] = __builtin_amdgcn_mfma_f32_16x16x32_bf16(a0, bf, acc[0][nt], 0, 0, 0);
            acc[1][nt] = __builtin_amdgcn_mfma_f32_16x16x32_bf16(a1, bf, acc[1][nt], 0, 0, 0);
        }
    }

    int rbase = (lane >> 4) * 4, col = lane & 15;
    #pragma unroll
    for (int i = 0; i < 2; i++)
        #pragma unroll
        for (int nt = 0; nt < 8; nt++)
            #pragma unroll
            for (int r = 0; r < 4; r++) {
                int m = m0 + w * 32 + i * 16 + rbase + r;
                int t = m >> 8, b = m & 255;
                fp[((size_t)b * NT + t) * HID + n0 + nt * 16 + col] = f2b(acc[i][nt][r]);
            }
}
__global__ __launch_bounds__(256) void fp_kernel(const void* feats, const void* i2h_w,
                                                 u16* fp, const int* flagp) {
    if (*flagp) fp_body((const u16*)feats, (const u16*)i2h_w, fp);
    else        fp_body((const float*)feats, (const float*)i2h_w, fp);
}

// ---------------- ROI-align 2x2
template <typename T>
__device__ __forceinline__ void do_crop(
    const T* __restrict__ f, int C, int H, int W,
    float x1, float y1, float x2, float y2,
    u16* __restrict__ xrow, int off, int tid)
{
    int n = C * 4;
    if (tid >= n) return;
    float bw = fmaxf(x2 - x1, 1.f) * 0.5f;
    float bh = fmaxf(y2 - y1, 1.f) * 0.5f;
    int c = tid >> 2, iy = (tid >> 1) & 1, ix = tid & 1;
    float yy = y1 + (0.5f + (float)iy) * bh;
    float xx = x1 + (0.5f + (float)ix) * bw;
    bool valid = (yy >= -1.f) && (yy <= (float)H) && (xx <= (float)W) && (xx >= -1.f);
    float y = fminf(fmaxf(yy, 0.f), (float)(H - 1));
    float x = fminf(fmaxf(xx, 0.f), (float)(W - 1));
    float y0f = floorf(y), x0f = floorf(x);
    int y0 = (int)y0f, x0 = (int)x0f;
    int y1i = min(y0 + 1, H - 1), x1i = min(x0 + 1, W - 1);
    float ly = y - y0f, lx = x - x0f, hy = 1.f - ly, hx = 1.f - lx;
    size_t base = (size_t)c * H * W;
    float v = ldf(f, base + y0 * W + x0) * hy * hx + ldf(f, base + y0 * W + x1i) * hy * lx
            + ldf(f, base + y1i * W + x0) * ly * hx + ldf(f, base + y1i * W + x1i) * ly * lx;
    xrow[off + tid] = f2b(valid ? v : 0.f);
}

// ---------------- attention step: one block (512 thr) per batch element.
// hp GEMV fused (packed-T h2h weights prefetched to 64 VGPRs). All big inputs
// prefetched into registers before the first barrier; later phases are
// VALU/LDS-only. NOTE: plain __launch_bounds__(512) -- no occupancy arg, so the
// compiler may use up to 256 VGPR (the (512,2) form capped at 128 and spilled).
template <typename T>
__device__ void attn_body(
    const u16* pt,
    const T* pyr0, const T* pyr1, const T* pyr2,
    const int* text,
    const T* h2h_b, const T* score_w,
    const T* pose_w, const T* pose_b, const T* char_emb,
    const u16* h2h_wT, const u16* ft, const u16* fp,
    const u16* h_cur, u16* xout, int s)
{
    const int b = blockIdx.x;
    const int tid = threadIdx.x;
    __shared__ __align__(16) float smem[2708];
    float* h_s    = smem;          // 256
    float* hp_s   = smem + 256;    // 264 (skewed)
    float* sw_s   = smem + 520;    // 264 (skewed)
    float* ep_s   = smem + 784;    // 512
    float* pp_s   = smem + 1296;   // 512
    float* e_s    = smem + 1808;   // 128 (alpha)
    float* ctx_s  = smem + 1936;   // 768
    float* coord_s= smem + 2704;   // 4

    // ---- prologue: issue loads in consumption order (vmcnt is FIFO)
    float hv = 0.f, swv = 0.f;
    if (tid < 256) hv = b2f(h_cur[b * HID + tid]);
    else           swv = ldf(score_w, tid - 256);

    // hp weights: thread (j = tid&255, half = tid>>8), coalesced u32 (2 k each)
    u32 wv[64];
    {
        const u16* wp = h2h_wT + 2 * (tid & 255) + (size_t)(tid >> 8) * 64 * 512;
        #pragma unroll
        for (int i = 0; i < 64; i++) wv[i] = *(const u32*)(wp + i * 512);
    }

    // e-phase fp slice: thread (t = tid>>2, q = tid&3) covers h in [q*64, q*64+64)
    const int t_e = tid >> 2, q_e = tid & 3;
    const u16* fpr = fp + ((size_t)b * NT + t_e) * HID + q_e * 64;
    short8 fpv[8];
    #pragma unroll
    for (int i = 0; i < 8; i++) fpv[i] = *(const short8*)(fpr + 8 * i);

    // ctx-feats slice: channel c = tid, all 128 t
    const u16* ftr = ft + ((size_t)b * NC + tid) * NT;
    short8 ftv[16];
    #pragma unroll
    for (int i = 0; i < 16; i++) ftv[i] = *(const short8*)(ftr + 8 * i);

    int tgt = 0;
    if (s > 0) tgt = text[b * NSTEPS + (s - 1)] + 1;
    float embv = 0.f;
    if (tid >= 256 && tid < 256 + EMB)
        embv = ldf(char_emb, (size_t)tgt * EMB + (tid - 256));

    // ---- stage h + sw into LDS
    if (tid < 256) h_s[tid] = hv;
    else { int k = tid - 256; sw_s[k + (k >> 5)] = swv; }
    __syncthreads();

    // ---- hp GEMV (weights in regs; h_s reads are wave-broadcast)
    {
        int base = (tid >> 8) * 128;
        float acc = 0.f;
        #pragma unroll
        for (int i = 0; i < 64; i++) {
            u32 w2 = wv[i];
            acc += h_s[base + 2 * i] * b2f((u16)w2)
                 + h_s[base + 2 * i + 1] * b2f((u16)(w2 >> 16));
        }
        ep_s[tid] = acc;
    }
    __syncthreads();
    if (tid < 256) hp_s[tid + (tid >> 5)] = ep_s[tid] + ep_s[tid + 256] + ldf(h2h_b, tid);
    __syncthreads();

    // ---- e partial: acc over 64 h
    {
        float acc = 0.f;
        #pragma unroll
        for (int i = 0; i < 8; i++) {
            short8 v = fpv[i];
            #pragma unroll
            for (int j = 0; j < 8; j++) {
                int h = q_e * 64 + i * 8 + j;
                int ki = h + (h >> 5);
                acc += ftanh(b2f((u16)v[j]) + hp_s[ki]) * sw_s[ki];
            }
        }
        ep_s[tid] = acc;
    }
    __syncthreads();

    // ---- e-combine + softmax, wave 0 only
    if (tid < 64) {
        float4 a = *(const float4*)&ep_s[4 * tid];
        float4 c = *(const float4*)&ep_s[4 * (tid + 64)];
        float eL = a.x + a.y + a.z + a.w;
        float eH = c.x + c.y + c.z + c.w;
        float m = fmaxf(eL, eH);
        #pragma unroll
        for (int off = 32; off; off >>= 1) m = fmaxf(m, __shfl_xor(m, off));
        float pL = __expf(eL - m), pH = __expf(eH - m);
        float sm = pL + pH;
        #pragma unroll
        for (int off = 32; off; off >>= 1) sm += __shfl_xor(sm, off);
        float inv = 1.f / sm;
        e_s[tid] = pL * inv;
        e_s[tid + 64] = pH * inv;
    }
    __syncthreads();

    u16* xr = xout + (size_t)b * RNN_IN;

    // ---- ctx feats (pure VALU: ftv regs x alpha from LDS broadcast)
    {
        float acc = 0.f;
        #pragma unroll
        for (int i = 0; i < 16; i++) {
            float4 a0 = *(const float4*)&e_s[8 * i];
            float4 a1 = *(const float4*)&e_s[8 * i + 4];
            short8 v = ftv[i];
            acc += a0.x * b2f((u16)v[0]) + a0.y * b2f((u16)v[1])
                 + a0.z * b2f((u16)v[2]) + a0.w * b2f((u16)v[3])
                 + a1.x * b2f((u16)v[4]) + a1.y * b2f((u16)v[5])
                 + a1.z * b2f((u16)v[6]) + a1.w * b2f((u16)v[7]);
        }
        ctx_s[tid] = acc;
        xr[tid] = f2b(acc);
    }
    // ---- ctx pose partial (streamed: L2/L3-hot)
    {
        const int p_c = tid & 255, hf = tid >> 8;
        const u16* pr = pt + ((size_t)b * POSEC + p_c) * NT + hf * 64;
        float acc = 0.f;
        #pragma unroll
        for (int i = 0; i < 8; i++) {
            short8 v = *(const short8*)(pr + 8 * i);
            float4 a0 = *(const float4*)&e_s[hf * 64 + 8 * i];
            float4 a1 = *(const float4*)&e_s[hf * 64 + 8 * i + 4];
            acc += a0.x * b2f((u16)v[0]) + a0.y * b2f((u16)v[1])
                 + a0.z * b2f((u16)v[2]) + a0.w * b2f((u16)v[3])
                 + a1.x * b2f((u16)v[4]) + a1.y * b2f((u16)v[5])
                 + a1.z * b2f((u16)v[6]) + a1.w * b2f((u16)v[7]);
        }
        pp_s[tid] = acc;
    }
    // emb write (independent)
    if (tid >= 256 && tid < 256 + EMB) xr[768 + (tid - 256)] = f2b(embv);
    __syncthreads();
    if (tid < 256) {
        float v = pp_s[tid] + pp_s[tid + 256];
        ctx_s[512 + tid] = v;
        xr[512 + tid] = f2b(v);
    }
    __syncthreads();

    // ---- coord = sigmoid(ctx @ pose_w.T + pose_b)  (streamed weights, L2-hot)
    if (tid < 256) {
        int j = tid >> 6, lane = tid & 63;
        float acc = 0.f;
        #pragma unroll
        for (int k = 0; k < 12; k++)
            acc += ctx_s[lane + k * 64] * ldf(pose_w, (size_t)j * 768 + k * 64 + lane);
        #pragma unroll
        for (int off = 32; off; off >>= 1) acc += __shfl_down(acc, off);
        if (lane == 0) coord_s[j] = sigm(acc + ldf(pose_b, j));
    }
    __syncthreads();

    float c0 = coord_s[0], c1 = coord_s[1], c2 = coord_s[2], c3 = coord_s[3];
    // crops in disjoint thread ranges (<=2 serial crops per thread)
    if (tid < 64) {
        do_crop(pyr0, 16, 16, 128, c0 * 16.f,  c1 * 128.f,    c2 * 16.f,  c3 * 128.f,    xr, 896,  tid);
        do_crop(pyr2, 64, 4,  65,  c0 * 512.f, c1 * 532480.f, c2 * 512.f, c3 * 532480.f, xr, 1216, tid + 192);
    } else if (tid < 320) {
        do_crop(pyr1, 64, 8,  64,  c0 * 128.f, c1 * 8192.f,   c2 * 128.f, c3 * 8192.f,   xr, 960,  tid - 64);
    } else {
        do_crop(pyr2, 64, 4,  65,  c0 * 512.f, c1 * 532480.f, c2 * 512.f, c3 * 532480.f, xr, 1216, tid - 320);
    }
}

__global__ __launch_bounds__(512) void attn_kernel(
    const u16* pt,
    const void* pyr0, const void* pyr1, const void* pyr2,
    const int* text,
    const void* h2h_b, const void* score_w,
    const void* pose_w, const void* pose_b, const void* char_emb,
    const u16* h2h_wT, const u16* ft, const u16* fp,
    const u16* h_cur, u16* xout, int s, const int* flagp)
{
    if (*flagp)
        attn_body(pt, (const u16*)pyr0, (const u16*)pyr1,
                  (const u16*)pyr2, text, (const u16*)h2h_b, (const u16*)score_w,
                  (const u16*)pose_w, (const u16*)pose_b, (const u16*)char_emb,
                  h2h_wT, ft, fp, h_cur, xout, s);
    else
        attn_body(pt, (const float*)pyr0, (const float*)pyr1,
                  (const float*)pyr2, text, (const float*)h2h_b, (const float*)score_w,
                  (const float*)pose_w, (const float*)pose_b, (const float*)char_emb,
                  h2h_wT, ft, fp, h_cur, xout, s);
}

// ---------------- GRU step: grid (16 jt, 16 bt), 8 waves split K, fused r/z acc
template <typename T>
__device__ void gru_body(
    const u16* x, const u16* h_prev, u16* h_new,
    const u16* w_ih, const u16* w_hh, const T* b_ih, const T* b_hh)
{
    const int jt = blockIdx.x, bt = blockIdx.y;
    const int tid = threadIdx.x;
    const int w = tid >> 6, lane = tid & 63;
    const int lr = lane & 15;
    const int kq = (lane >> 4) * 8;
    const int arow = bt * 16 + lr;

    floatx4 acc_r = {0.f,0.f,0.f,0.f}, acc_z = acc_r, acc_in = acc_r, acc_hn = acc_r;

    for (int kc = w; kc < RNN_IN / 32; kc += 8) {
        int k0 = kc * 32 + kq;
        short8 a = *(const short8*)(x + (size_t)arow * RNN_IN + k0);
        short8 b0 = *(const short8*)(w_ih + (size_t)(0 * HID + jt * 16 + lr) * RNN_IN + k0);
        short8 b1 = *(const short8*)(w_ih + (size_t)(1 * HID + jt * 16 + lr) * RNN_IN + k0);
        short8 b2 = *(const short8*)(w_ih + (size_t)(2 * HID + jt * 16 + lr) * RNN_IN + k0);
        acc_r  = __builtin_amdgcn_mfma_f32_16x16x32_bf16(a, b0, acc_r, 0, 0, 0);
        acc_z  = __builtin_amdgcn_mfma_f32_16x16x32_bf16(a, b1, acc_z, 0, 0, 0);
        acc_in = __builtin_amdgcn_mfma_f32_16x16x32_bf16(a, b2, acc_in, 0, 0, 0);
    }
    for (int kc = w; kc < HID / 32; kc += 8) {
        int k0 = kc * 32 + kq;
        short8 a = *(const short8*)(h_prev + (size_t)arow * HID + k0);
        short8 b0 = *(const short8*)(w_hh + (size_t)(0 * HID + jt * 16 + lr) * HID + k0);
        short8 b1 = *(const short8*)(w_hh + (size_t)(1 * HID + jt * 16 + lr) * HID + k0);
        short8 b2 = *(const short8*)(w_hh + (size_t)(2 * HID + jt * 16 + lr) * HID + k0);
        acc_r  = __builtin_amdgcn_mfma_f32_16x16x32_bf16(a, b0, acc_r, 0, 0, 0);
        acc_z  = __builtin_amdgcn_mfma_f32_16x16x32_bf16(a, b1, acc_z, 0, 0, 0);
        acc_hn = __builtin_amdgcn_mfma_f32_16x16x32_bf16(a, b2, acc_hn, 0, 0, 0);
    }

    extern __shared__ float red[];  // [8][4][16][17]
    int jcol = lane & 15, rb = (lane >> 4) * 4;
    #pragma unroll
    for (int r = 0; r < 4; r++) {
        red[((w * 4 + 0) * 16 + jcol) * 17 + rb + r] = acc_r[r];
        red[((w * 4 + 1) * 16 + jcol) * 17 + rb + r] = acc_z[r];
        red[((w * 4 + 2) * 16 + jcol) * 17 + rb + r] = acc_in[r];
        red[((w * 4 + 3) * 16 + jcol) * 17 + rb + r] = acc_hn[r];
    }
    __syncthreads();

    if (tid < 256) {
        int jj = tid >> 4, bl = tid & 15;
        float sr = 0, sz = 0, sin_ = 0, shn = 0;
        #pragma unroll
        for (int w2 = 0; w2 < 8; w2++) {
            sr   += red[((w2 * 4 + 0) * 16 + jj) * 17 + bl];
            sz   += red[((w2 * 4 + 1) * 16 + jj) * 17 + bl];
            sin_ += red[((w2 * 4 + 2) * 16 + jj) * 17 + bl];
            shn  += red[((w2 * 4 + 3) * 16 + jj) * 17 + bl];
        }
        int j = jt * 16 + jj, b = bt * 16 + bl;
        float r  = sigm(sr + ldf(b_ih, j) + ldf(b_hh, j));
        float zz = sigm(sz + ldf(b_ih, j + 256) + ldf(b_hh, j + 256));
        float n  = ftanh(sin_ + ldf(b_ih, j + 512) + r * (shn + ldf(b_hh, j + 512)));
        float hp = b2f(h_prev[(size_t)b * HID + j]);
        h_new[(size_t)b * HID + j] = f2b((1.f - zz) * n + zz * hp);
    }
}

__global__ __launch_bounds__(512) void gru_kernel(
    const u16* x, const u16* h_prev, u16* h_new,
    const u16* w_ih, const u16* w_hh,
    const void* b_ih, const void* b_hh, const int* flagp)
{
    if (*flagp) gru_body(x, h_prev, h_new, w_ih, w_hh, (const u16*)b_ih, (const u16*)b_hh);
    else        gru_body(x, h_prev, h_new, w_ih, w_hh, (const float*)b_ih, (const float*)b_hh);
}

// ---------------- final classifier
template <typename T>
__device__ void gen_body(const u16* hs, const T* gen_w, const T* gen_b, void* out) {
    int rowid = blockIdx.x;
    int b = rowid / NSTEPS, s = rowid % NSTEPS;
    const u16* h = hs + ((size_t)(s + 1) * NB + b) * HID;
    extern __shared__ float hsd[];
    int tid = threadIdx.x;
    for (int i = tid; i < HID; i += 64) hsd[i] = b2f(h[i]);
    __syncthreads();
    if (tid < NCLS) {
        float acc = ldf(gen_b, tid);
        const T* wr = gen_w + (size_t)tid * HID;
        #pragma unroll 4
        for (int k4 = 0; k4 < HID / 4; k4++) {
            float4 wv = ld4(wr + 4 * k4);
            acc += hsd[4 * k4 + 0] * wv.x + hsd[4 * k4 + 1] * wv.y
                 + hsd[4 * k4 + 2] * wv.z + hsd[4 * k4 + 3] * wv.w;
        }
        size_t o = (size_t)rowid * NCLS + tid;
        if (sizeof(T) == 2) ((u16*)out)[o] = f2b(acc);
        else                ((float*)out)[o] = acc;
    }
}
__global__ __launch_bounds__(64) void gen_kernel(
    const u16* hs, const void* gen_w, const void* gen_b, void* out, const int* flagp)
{
    if (*flagp) gen_body(hs, (const u16*)gen_w, (const u16*)gen_b, out);
    else        gen_body(hs, (const float*)gen_w, (const float*)gen_b, out);
}

extern "C" void kernel_launch(void* const* d_in, const int* in_sizes, int n_in,
                              void* d_out, int out_size, void* d_ws, size_t ws_size,
                              hipStream_t stream) {
    (void)in_sizes; (void)n_in; (void)out_size;
    const int* text = (const int*)d_in[6];

    char* ws = (char*)d_ws;
    size_t off = 256;
    int* flag = (int*)ws;
    u16* fp = (u16*)(ws + off); off += (size_t)NB * NT * HID * 2;        // 16.78 MB
    u16* ft = (u16*)(ws + off); off += (size_t)NB * NC * NT * 2;         // 33.55 MB
    u16* hs     = (u16*)(ws + off); off += 3407872;
    u16* x      = (u16*)(ws + off); off += 753664;
    u16* wih_c  = (u16*)(ws + off); off += 2260992;
    u16* whh_c  = (u16*)(ws + off); off += 393216;
    u16* h2h_wT = (u16*)(ws + off); off += 131072;
    u16* pt     = (u16*)(ws + off); off += (size_t)NB * POSEC * NT * 2;  // 16.78 MB

    probe_kernel<<<1, 128, 0, stream>>>(d_in[10], flag);
    conv_kernel<<<512, 256, 0, stream>>>(d_in[13], d_in[14], d_in[8],
                                         wih_c, whh_c, h2h_wT, flag);
    hipMemsetAsync(hs, 0, (size_t)NB * HID * 2, stream);  // h0 = 0
    fp_kernel<<<dim3(256, 2), 256, 0, stream>>>(d_in[0], d_in[7], fp, flag);
    trans_kernel<<<dim3(NB, NT / 8), 256, 0, stream>>>(d_in[0], ft, flag);
    pconv_kernel<<<2048, 256, 0, stream>>>(d_in[1], pt, flag);

    for (int s = 0; s < NSTEPS; s++) {
        attn_kernel<<<NB, 512, 0, stream>>>(
            pt, d_in[2], d_in[3], d_in[4], text,
            d_in[9], d_in[10], d_in[11], d_in[12], d_in[17],
            h2h_wT, ft, fp, hs + (size_t)s * NB * HID, x, s, flag);
        gru_kernel<<<dim3(16, 16), 512, 34816, stream>>>(
            x, hs + (size_t)s * NB * HID, hs + (size_t)(s + 1) * NB * HID,
            wih_c, whh_c, d_in[15], d_in[16], flag);
    }
    gen_kernel<<<NB * NSTEPS, 64, 1024, stream>>>(hs, d_in[18], d_in[19], d_out, flag);
}

// Round 5
// 1036.633 us; speedup vs baseline: 4.5968x; 1.0049x over previous
//
#include <hip/hip_runtime.h>
#include <hip/hip_bf16.h>

typedef unsigned short u16;
typedef unsigned int u32;
typedef __attribute__((ext_vector_type(8))) short short8;
typedef __attribute__((ext_vector_type(4))) float floatx4;

#define NT 128
#define NB 256
#define NC 512
#define HID 256
#define EMB 128
#define NCLS 37
#define NSTEPS 25
#define POSEC 256
#define RNN_IN 1472

__device__ __forceinline__ float b2f(u16 u) {
    union { float f; u32 i; } v; v.i = ((u32)u) << 16; return v.f;
}
__device__ __forceinline__ u16 f2b(float f) {
    union { float f; u32 i; } v; v.f = f;
    u32 x = v.i;
    return (u16)((x + 0x7fffu + ((x >> 16) & 1u)) >> 16);  // RNE
}
__device__ __forceinline__ float sigm(float x) { return 1.f / (1.f + __expf(-x)); }

// fast tanh: (1 - e^{-2|x|}) / (1 + e^{-2|x|}) with sign restore
__device__ __forceinline__ float ftanh(float x) {
    float t = __expf(-2.f * fabsf(x));
    float r = (1.f - t) * __builtin_amdgcn_rcpf(1.f + t);
    return copysignf(r, x);
}

// dtype-polymorphic loads
__device__ __forceinline__ float ldf(const float* p, size_t i) { return p[i]; }
__device__ __forceinline__ float ldf(const u16* p, size_t i) { return b2f(p[i]); }

__device__ __forceinline__ short8 ld8(const u16* p) { return *(const short8*)p; }
__device__ __forceinline__ short8 ld8(const float* p) {
    float4 a = *(const float4*)p; float4 b = *(const float4*)(p + 4);
    short8 r;
    r[0] = (short)f2b(a.x); r[1] = (short)f2b(a.y); r[2] = (short)f2b(a.z); r[3] = (short)f2b(a.w);
    r[4] = (short)f2b(b.x); r[5] = (short)f2b(b.y); r[6] = (short)f2b(b.z); r[7] = (short)f2b(b.w);
    return r;
}
__device__ __forceinline__ float4 ld4(const float* p) { return *(const float4*)p; }
__device__ __forceinline__ float4 ld4(const u16* p) {
    ushort4 v = *(const ushort4*)p;
    return make_float4(b2f(v.x), b2f(v.y), b2f(v.z), b2f(v.w));
}

// ---------------- dtype probe (1 = bf16, 0 = f32)
__global__ void probe_kernel(const void* score_w, int* flag) {
    __shared__ float red[128];
    int tid = threadIdx.x;
    const u16* p = (const u16*)score_w;
    float v = fabsf(b2f(p[tid]));
    v = (v == v && v < 1e6f) ? v : 1e6f;
    red[tid] = v;
    __syncthreads();
    for (int s2 = 64; s2 > 0; s2 >>= 1) {
        if (tid < s2) red[tid] += red[tid + s2];
        __syncthreads();
    }
    if (tid == 0) flag[0] = (red[0] < 1000.f) ? 1 : 0;
}

// ---------------- canonicalize GRU weights to bf16 + pack h2h_w transposed
// h2h_wT packed: out[(c>>1)*512 + 2*j + (c&1)] = h2h_w[j][c]
__global__ void conv_kernel(const void* w_ih, const void* w_hh, const void* h2h_w,
                            u16* out_ih, u16* out_hh, u16* out_h2h, const int* flagp) {
    int f = *flagp;
    int idx = blockIdx.x * blockDim.x + threadIdx.x;
    int stride = gridDim.x * blockDim.x;
    const int n_ih = 768 * RNN_IN, n_hh = 768 * HID, n_h2h = HID * HID;
    if (f) {
        const u16* a = (const u16*)w_ih; const u16* b = (const u16*)w_hh;
        const u16* c = (const u16*)h2h_w;
        for (int i = idx; i < n_ih; i += stride) out_ih[i] = a[i];
        for (int i = idx; i < n_hh; i += stride) out_hh[i] = b[i];
        for (int i = idx; i < n_h2h; i += stride) {
            int j = i >> 8, cc = i & 255;
            out_h2h[(cc >> 1) * 512 + (j << 1) + (cc & 1)] = c[i];
        }
    } else {
        const float* a = (const float*)w_ih; const float* b = (const float*)w_hh;
        const float* c = (const float*)h2h_w;
        for (int i = idx; i < n_ih; i += stride) out_ih[i] = f2b(a[i]);
        for (int i = idx; i < n_hh; i += stride) out_hh[i] = f2b(b[i]);
        for (int i = idx; i < n_h2h; i += stride) {
            int j = i >> 8, cc = i & 255;
            out_h2h[(cc >> 1) * 512 + (j << 1) + (cc & 1)] = f2b(c[i]);
        }
    }
}

// ---------------- pose (b,p,1,t) -> bf16 pt[b][p][t]  (read 25x, convert once)
template <typename T>
__device__ void pconv_body(const T* pose, u16* pt) {
    size_t n = (size_t)NB * POSEC * NT;
    size_t i = ((size_t)blockIdx.x * blockDim.x + threadIdx.x) * 4;
    size_t stride = (size_t)gridDim.x * blockDim.x * 4;
    for (; i < n; i += stride) {
        float4 v = ld4(pose + i);
        ushort4 o;
        o.x = f2b(v.x); o.y = f2b(v.y); o.z = f2b(v.z); o.w = f2b(v.w);
        *(ushort4*)(pt + i) = o;
    }
}
__global__ __launch_bounds__(256) void pconv_kernel(const void* pose, u16* pt, const int* flagp) {
    if (*flagp) pconv_body((const u16*)pose, pt);
    else        pconv_body((const float*)pose, pt);
}

// ---------------- transpose feats (t,b,c) -> ft[b][c][t]
template <typename T>
__device__ void trans_body(const T* feats, u16* ft) {
    int b = blockIdx.x, t0 = blockIdx.y * 8;
    #pragma unroll
    for (int half = 0; half < 2; half++) {
        int c = threadIdx.x + half * 256;
        short8 v;
        #pragma unroll
        for (int j = 0; j < 8; j++)
            v[j] = (short)f2b(ldf(feats, ((size_t)(t0 + j) * NB + b) * NC + c));
        *(short8*)(ft + ((size_t)b * NC + c) * NT + t0) = v;
    }
}
__global__ __launch_bounds__(256) void trans_kernel(const void* feats, u16* ft, const int* flagp) {
    if (*flagp) trans_body((const u16*)feats, ft);
    else        trans_body((const float*)feats, ft);
}

// ---------------- feats_proj: LDS-tiled MFMA GEMM, 128x256 tile (full N), BK=32
// Single pass over A (halves A traffic vs the old grid-(256,2) version).
// 512 threads = 8 waves in 2(m) x 4(n); per-wave 64x64 out = acc[4][4].
template <typename T>
__device__ void fp_body(const T* feats, const T* i2h_w, u16* fp) {
    __shared__ u16 As[128][40];   // +8 pad
    __shared__ u16 Bs[256][40];
    const int tid = threadIdx.x;
    const int w = tid >> 6, lane = tid & 63;
    const int wm = w >> 2, wn = w & 3;
    const int m0 = blockIdx.x * 128;
    const int lr = lane & 15, kq = (lane >> 4) * 8;
    const int arow = tid >> 2, achunk = (tid & 3) * 8;
    const int brow = tid >> 1, bchunk = (tid & 1) * 16;

    floatx4 acc[4][4];
    #pragma unroll
    for (int mt = 0; mt < 4; mt++)
        #pragma unroll
        for (int nt = 0; nt < 4; nt++) acc[mt][nt] = (floatx4){0.f, 0.f, 0.f, 0.f};

    for (int kk = 0; kk < NC; kk += 32) {
        short8 av  = ld8(feats + (size_t)(m0 + arow) * NC + kk + achunk);
        short8 bv0 = ld8(i2h_w + (size_t)brow * NC + kk + bchunk);
        short8 bv1 = ld8(i2h_w + (size_t)brow * NC + kk + bchunk + 8);
        __syncthreads();
        *(short8*)&As[arow][achunk] = av;
        *(short8*)&Bs[brow][bchunk] = bv0;
        *(short8*)&Bs[brow][bchunk + 8] = bv1;
        __syncthreads();
        short8 af[4];
        #pragma unroll
        for (int mt = 0; mt < 4; mt++)
            af[mt] = *(const short8*)&As[wm * 64 + mt * 16 + lr][kq];
        #pragma unroll
        for (int nt = 0; nt < 4; nt++) {
            short8 bf = *(const short8*)&Bs[wn * 64 + nt * 16 + lr][kq];
            #pragma unroll
            for (int mt = 0; mt < 4; mt++)
                acc[mt][nt] = __builtin_amdgcn_mfma_f32_16x16x32_bf16(af[mt], bf, acc[mt][nt], 0, 0, 0);
        }
    }

    int rbase = (lane >> 4) * 4, col = lane & 15;
    #pragma unroll
    for (int mt = 0; mt < 4; mt++)
        #pragma unroll
        for (int nt = 0; nt < 4; nt++)
            #pragma unroll
            for (int r = 0; r < 4; r++) {
                int m = m0 + wm * 64 + mt * 16 + rbase + r;
                int t = m >> 8, b = m & 255;
                int h = wn * 64 + nt * 16 + col;
                fp[((size_t)b * NT + t) * HID + h] = f2b(acc[mt][nt][r]);
            }
}
__global__ __launch_bounds__(512) void fp_kernel(const void* feats, const void* i2h_w,
                                                 u16* fp, const int* flagp) {
    if (*flagp) fp_body((const u16*)feats, (const u16*)i2h_w, fp);
    else        fp_body((const float*)feats, (const float*)i2h_w, fp);
}

// ---------------- ROI-align 2x2
template <typename T>
__device__ __forceinline__ void do_crop(
    const T* __restrict__ f, int C, int H, int W,
    float x1, float y1, float x2, float y2,
    u16* __restrict__ xrow, int off, int tid)
{
    int n = C * 4;
    if (tid >= n) return;
    float bw = fmaxf(x2 - x1, 1.f) * 0.5f;
    float bh = fmaxf(y2 - y1, 1.f) * 0.5f;
    int c = tid >> 2, iy = (tid >> 1) & 1, ix = tid & 1;
    float yy = y1 + (0.5f + (float)iy) * bh;
    float xx = x1 + (0.5f + (float)ix) * bw;
    bool valid = (yy >= -1.f) && (yy <= (float)H) && (xx <= (float)W) && (xx >= -1.f);
    float y = fminf(fmaxf(yy, 0.f), (float)(H - 1));
    float x = fminf(fmaxf(xx, 0.f), (float)(W - 1));
    float y0f = floorf(y), x0f = floorf(x);
    int y0 = (int)y0f, x0 = (int)x0f;
    int y1i = min(y0 + 1, H - 1), x1i = min(x0 + 1, W - 1);
    float ly = y - y0f, lx = x - x0f, hy = 1.f - ly, hx = 1.f - lx;
    size_t base = (size_t)c * H * W;
    float v = ldf(f, base + y0 * W + x0) * hy * hx + ldf(f, base + y0 * W + x1i) * hy * lx
            + ldf(f, base + y1i * W + x0) * ly * hx + ldf(f, base + y1i * W + x1i) * ly * lx;
    xrow[off + tid] = f2b(valid ? v : 0.f);
}

// ---------------- attention step: one block (512 thr) per batch element.
// hp GEMV fused; ALL big streams (h2h weights, fp, ft, pt slices, pose_w, emb)
// prefetched into registers in consumption order before the first barrier.
// 7 barriers (pose-combine folded into the coord phase).
template <typename T>
__device__ void attn_body(
    const u16* pt,
    const T* pyr0, const T* pyr1, const T* pyr2,
    const int* text,
    const T* h2h_b, const T* score_w,
    const T* pose_w, const T* pose_b, const T* char_emb,
    const u16* h2h_wT, const u16* ft, const u16* fp,
    const u16* h_cur, u16* xout, int s)
{
    const int b = blockIdx.x;
    const int tid = threadIdx.x;
    __shared__ __align__(16) float smem[2452];
    float* h_s    = smem;          // 256
    float* hp_s   = smem + 256;    // 264 (skewed)
    float* sw_s   = smem + 520;    // 264 (skewed)
    float* ep_s   = smem + 784;    // 512
    float* pp_s   = smem + 1296;   // 512
    float* e_s    = smem + 1808;   // 128 (alpha)
    float* ctx_s  = smem + 1936;   // 512 (feats part only)
    float* coord_s= smem + 2448;   // 4

    // ---- prologue: issue loads in consumption order (vmcnt is FIFO)
    float hv = 0.f, swv = 0.f;
    if (tid < 256) hv = b2f(h_cur[b * HID + tid]);
    else           swv = ldf(score_w, tid - 256);

    // hp weights: thread (j = tid&255, half = tid>>8), coalesced u32 (2 k each)
    u32 wv[64];
    {
        const u16* wp = h2h_wT + 2 * (tid & 255) + (size_t)(tid >> 8) * 64 * 512;
        #pragma unroll
        for (int i = 0; i < 64; i++) wv[i] = *(const u32*)(wp + i * 512);
    }

    // e-phase fp slice: thread (t = tid>>2, q = tid&3) covers h in [q*64, q*64+64)
    const int t_e = tid >> 2, q_e = tid & 3;
    const u16* fpr = fp + ((size_t)b * NT + t_e) * HID + q_e * 64;
    short8 fpv[8];
    #pragma unroll
    for (int i = 0; i < 8; i++) fpv[i] = *(const short8*)(fpr + 8 * i);

    // ctx-feats slice: channel c = tid, all 128 t
    const u16* ftr = ft + ((size_t)b * NC + tid) * NT;
    short8 ftv[16];
    #pragma unroll
    for (int i = 0; i < 16; i++) ftv[i] = *(const short8*)(ftr + 8 * i);

    // ctx-pose slice: p = tid&255, t-half = tid>>8
    const int p_c = tid & 255, hf = tid >> 8;
    const u16* ptr_ = pt + ((size_t)b * POSEC + p_c) * NT + hf * 64;
    short8 ptv[8];
    #pragma unroll
    for (int i = 0; i < 8; i++) ptv[i] = *(const short8*)(ptr_ + 8 * i);

    // pose_w rows for the coord phase (threads < 256)
    float pwv[12];
    {
        int j = (tid >> 6) & 3, lane = tid & 63;
        #pragma unroll
        for (int k = 0; k < 12; k++)
            pwv[k] = (tid < 256) ? ldf(pose_w, (size_t)j * 768 + k * 64 + lane) : 0.f;
    }
    float pbv = (tid < 256 && (tid & 63) == 0) ? ldf(pose_b, tid >> 6) : 0.f;

    int tgt = 0;
    if (s > 0) tgt = text[b * NSTEPS + (s - 1)] + 1;
    float embv = 0.f;
    if (tid >= 256 && tid < 256 + EMB)
        embv = ldf(char_emb, (size_t)tgt * EMB + (tid - 256));

    // ---- stage h + sw into LDS
    if (tid < 256) h_s[tid] = hv;
    else { int k = tid - 256; sw_s[k + (k >> 5)] = swv; }
    __syncthreads();                                                     // (1)

    // ---- hp GEMV (weights in regs; h_s reads are wave-broadcast)
    {
        int base = (tid >> 8) * 128;
        float acc = 0.f;
        #pragma unroll
        for (int i = 0; i < 64; i++) {
            u32 w2 = wv[i];
            acc += h_s[base + 2 * i] * b2f((u16)w2)
                 + h_s[base + 2 * i + 1] * b2f((u16)(w2 >> 16));
        }
        ep_s[tid] = acc;
    }
    __syncthreads();                                                     // (2)
    if (tid < 256) hp_s[tid + (tid >> 5)] = ep_s[tid] + ep_s[tid + 256] + ldf(h2h_b, tid);
    __syncthreads();                                                     // (3)

    // ---- e partial: acc over 64 h
    {
        float acc = 0.f;
        #pragma unroll
        for (int i = 0; i < 8; i++) {
            short8 v = fpv[i];
            #pragma unroll
            for (int j = 0; j < 8; j++) {
                int h = q_e * 64 + i * 8 + j;
                int ki = h + (h >> 5);
                acc += ftanh(b2f((u16)v[j]) + hp_s[ki]) * sw_s[ki];
            }
        }
        ep_s[tid] = acc;
    }
    __syncthreads();                                                     // (4)

    // ---- e-combine + softmax, wave 0 only
    if (tid < 64) {
        float4 a = *(const float4*)&ep_s[4 * tid];
        float4 c = *(const float4*)&ep_s[4 * (tid + 64)];
        float eL = a.x + a.y + a.z + a.w;
        float eH = c.x + c.y + c.z + c.w;
        float m = fmaxf(eL, eH);
        #pragma unroll
        for (int off = 32; off; off >>= 1) m = fmaxf(m, __shfl_xor(m, off));
        float pL = __expf(eL - m), pH = __expf(eH - m);
        float sm = pL + pH;
        #pragma unroll
        for (int off = 32; off; off >>= 1) sm += __shfl_xor(sm, off);
        float inv = 1.f / sm;
        e_s[tid] = pL * inv;
        e_s[tid + 64] = pH * inv;
    }
    __syncthreads();                                                     // (5)

    u16* xr = xout + (size_t)b * RNN_IN;

    // ---- ctx feats (pure VALU: ftv regs x alpha from LDS broadcast)
    {
        float acc = 0.f;
        #pragma unroll
        for (int i = 0; i < 16; i++) {
            float4 a0 = *(const float4*)&e_s[8 * i];
            float4 a1 = *(const float4*)&e_s[8 * i + 4];
            short8 v = ftv[i];
            acc += a0.x * b2f((u16)v[0]) + a0.y * b2f((u16)v[1])
                 + a0.z * b2f((u16)v[2]) + a0.w * b2f((u16)v[3])
                 + a1.x * b2f((u16)v[4]) + a1.y * b2f((u16)v[5])
                 + a1.z * b2f((u16)v[6]) + a1.w * b2f((u16)v[7]);
        }
        ctx_s[tid] = acc;
        xr[tid] = f2b(acc);
    }
    // ---- ctx pose partial (prefetched ptv regs)
    {
        float acc = 0.f;
        #pragma unroll
        for (int i = 0; i < 8; i++) {
            short8 v = ptv[i];
            float4 a0 = *(const float4*)&e_s[hf * 64 + 8 * i];
            float4 a1 = *(const float4*)&e_s[hf * 64 + 8 * i + 4];
            acc += a0.x * b2f((u16)v[0]) + a0.y * b2f((u16)v[1])
                 + a0.z * b2f((u16)v[2]) + a0.w * b2f((u16)v[3])
                 + a1.x * b2f((u16)v[4]) + a1.y * b2f((u16)v[5])
                 + a1.z * b2f((u16)v[6]) + a1.w * b2f((u16)v[7]);
        }
        pp_s[tid] = acc;
    }
    // emb write (independent)
    if (tid >= 256 && tid < 256 + EMB) xr[768 + (tid - 256)] = f2b(embv);
    __syncthreads();                                                     // (6)

    // ---- coord (tid<256, reads pp_s pairs directly)  ||  pose-x writes (tid>=256)
    if (tid < 256) {
        int lane = tid & 63;
        float acc = 0.f;
        #pragma unroll
        for (int k = 0; k < 8; k++)
            acc += ctx_s[lane + k * 64] * pwv[k];
        #pragma unroll
        for (int k = 8; k < 12; k++) {
            int p = lane + (k - 8) * 64;
            acc += (pp_s[p] + pp_s[p + 256]) * pwv[k];
        }
        #pragma unroll
        for (int off = 32; off; off >>= 1) acc += __shfl_down(acc, off);
        if (lane == 0) coord_s[tid >> 6] = sigm(acc + pbv);
    } else {
        int p = tid - 256;
        xr[512 + p] = f2b(pp_s[p] + pp_s[p + 256]);
    }
    __syncthreads();                                                     // (7)

    float c0 = coord_s[0], c1 = coord_s[1], c2 = coord_s[2], c3 = coord_s[3];
    // crops in disjoint thread ranges (<=2 serial crops per thread)
    if (tid < 64) {
        do_crop(pyr0, 16, 16, 128, c0 * 16.f,  c1 * 128.f,    c2 * 16.f,  c3 * 128.f,    xr, 896,  tid);
        do_crop(pyr2, 64, 4,  65,  c0 * 512.f, c1 * 532480.f, c2 * 512.f, c3 * 532480.f, xr, 1216, tid + 192);
    } else if (tid < 320) {
        do_crop(pyr1, 64, 8,  64,  c0 * 128.f, c1 * 8192.f,   c2 * 128.f, c3 * 8192.f,   xr, 960,  tid - 64);
    } else {
        do_crop(pyr2, 64, 4,  65,  c0 * 512.f, c1 * 532480.f, c2 * 512.f, c3 * 532480.f, xr, 1216, tid - 320);
    }
}

__global__ __launch_bounds__(512) void attn_kernel(
    const u16* pt,
    const void* pyr0, const void* pyr1, const void* pyr2,
    const int* text,
    const void* h2h_b, const void* score_w,
    const void* pose_w, const void* pose_b, const void* char_emb,
    const u16* h2h_wT, const u16* ft, const u16* fp,
    const u16* h_cur, u16* xout, int s, const int* flagp)
{
    if (*flagp)
        attn_body(pt, (const u16*)pyr0, (const u16*)pyr1,
                  (const u16*)pyr2, text, (const u16*)h2h_b, (const u16*)score_w,
                  (const u16*)pose_w, (const u16*)pose_b, (const u16*)char_emb,
                  h2h_wT, ft, fp, h_cur, xout, s);
    else
        attn_body(pt, (const float*)pyr0, (const float*)pyr1,
                  (const float*)pyr2, text, (const float*)h2h_b, (const float*)score_w,
                  (const float*)pose_w, (const float*)pose_b, (const float*)char_emb,
                  h2h_wT, ft, fp, h_cur, xout, s);
}

// ---------------- GRU step: grid (16 jt, 16 bt), 8 waves split K, fused r/z acc
template <typename T>
__device__ void gru_body(
    const u16* x, const u16* h_prev, u16* h_new,
    const u16* w_ih, const u16* w_hh, const T* b_ih, const T* b_hh)
{
    const int jt = blockIdx.x, bt = blockIdx.y;
    const int tid = threadIdx.x;
    const int w = tid >> 6, lane = tid & 63;
    const int lr = lane & 15;
    const int kq = (lane >> 4) * 8;
    const int arow = bt * 16 + lr;

    floatx4 acc_r = {0.f,0.f,0.f,0.f}, acc_z = acc_r, acc_in = acc_r, acc_hn = acc_r;

    for (int kc = w; kc < RNN_IN / 32; kc += 8) {
        int k0 = kc * 32 + kq;
        short8 a = *(const short8*)(x + (size_t)arow * RNN_IN + k0);
        short8 b0 = *(const short8*)(w_ih + (size_t)(0 * HID + jt * 16 + lr) * RNN_IN + k0);
        short8 b1 = *(const short8*)(w_ih + (size_t)(1 * HID + jt * 16 + lr) * RNN_IN + k0);
        short8 b2 = *(const short8*)(w_ih + (size_t)(2 * HID + jt * 16 + lr) * RNN_IN + k0);
        acc_r  = __builtin_amdgcn_mfma_f32_16x16x32_bf16(a, b0, acc_r, 0, 0, 0);
        acc_z  = __builtin_amdgcn_mfma_f32_16x16x32_bf16(a, b1, acc_z, 0, 0, 0);
        acc_in = __builtin_amdgcn_mfma_f32_16x16x32_bf16(a, b2, acc_in, 0, 0, 0);
    }
    for (int kc = w; kc < HID / 32; kc += 8) {
        int k0 = kc * 32 + kq;
        short8 a = *(const short8*)(h_prev + (size_t)arow * HID + k0);
        short8 b0 = *(const short8*)(w_hh + (size_t)(0 * HID + jt * 16 + lr) * HID + k0);
        short8 b1 = *(const short8*)(w_hh + (size_t)(1 * HID + jt * 16 + lr) * HID + k0);
        short8 b2 = *(const short8*)(w_hh + (size_t)(2 * HID + jt * 16 + lr) * HID + k0);
        acc_r  = __builtin_amdgcn_mfma_f32_16x16x32_bf16(a, b0, acc_r, 0, 0, 0);
        acc_z  = __builtin_amdgcn_mfma_f32_16x16x32_bf16(a, b1, acc_z, 0, 0, 0);
        acc_hn = __builtin_amdgcn_mfma_f32_16x16x32_bf16(a, b2, acc_hn, 0, 0, 0);
    }

    extern __shared__ float red[];  // [8][4][16][17]
    int jcol = lane & 15, rb = (lane >> 4) * 4;
    #pragma unroll
    for (int r = 0; r < 4; r++) {
        red[((w * 4 + 0) * 16 + jcol) * 17 + rb + r] = acc_r[r];
        red[((w * 4 + 1) * 16 + jcol) * 17 + rb + r] = acc_z[r];
        red[((w * 4 + 2) * 16 + jcol) * 17 + rb + r] = acc_in[r];
        red[((w * 4 + 3) * 16 + jcol) * 17 + rb + r] = acc_hn[r];
    }
    __syncthreads();

    if (tid < 256) {
        int jj = tid >> 4, bl = tid & 15;
        float sr = 0, sz = 0, sin_ = 0, shn = 0;
        #pragma unroll
        for (int w2 = 0; w2 < 8; w2++) {
            sr   += red[((w2 * 4 + 0) * 16 + jj) * 17 + bl];
            sz   += red[((w2 * 4 + 1) * 16 + jj) * 17 + bl];
            sin_ += red[((w2 * 4 + 2) * 16 + jj) * 17 + bl];
            shn  += red[((w2 * 4 + 3) * 16 + jj) * 17 + bl];
        }
        int j = jt * 16 + jj, b = bt * 16 + bl;
        float r  = sigm(sr + ldf(b_ih, j) + ldf(b_hh, j));
        float zz = sigm(sz + ldf(b_ih, j + 256) + ldf(b_hh, j + 256));
        float n  = ftanh(sin_ + ldf(b_ih, j + 512) + r * (shn + ldf(b_hh, j + 512)));
        float hp = b2f(h_prev[(size_t)b * HID + j]);
        h_new[(size_t)b * HID + j] = f2b((1.f - zz) * n + zz * hp);
    }
}

__global__ __launch_bounds__(512) void gru_kernel(
    const u16* x, const u16* h_prev, u16* h_new,
    const u16* w_ih, const u16* w_hh,
    const void* b_ih, const void* b_hh, const int* flagp)
{
    if (*flagp) gru_body(x, h_prev, h_new, w_ih, w_hh, (const u16*)b_ih, (const u16*)b_hh);
    else        gru_body(x, h_prev, h_new, w_ih, w_hh, (const float*)b_ih, (const float*)b_hh);
}

// ---------------- final classifier
template <typename T>
__device__ void gen_body(const u16* hs, const T* gen_w, const T* gen_b, void* out) {
    int rowid = blockIdx.x;
    int b = rowid / NSTEPS, s = rowid % NSTEPS;
    const u16* h = hs + ((size_t)(s + 1) * NB + b) * HID;
    extern __shared__ float hsd[];
    int tid = threadIdx.x;
    for (int i = tid; i < HID; i += 64) hsd[i] = b2f(h[i]);
    __syncthreads();
    if (tid < NCLS) {
        float acc = ldf(gen_b, tid);
        const T* wr = gen_w + (size_t)tid * HID;
        #pragma unroll 4
        for (int k4 = 0; k4 < HID / 4; k4++) {
            float4 wv = ld4(wr + 4 * k4);
            acc += hsd[4 * k4 + 0] * wv.x + hsd[4 * k4 + 1] * wv.y
                 + hsd[4 * k4 + 2] * wv.z + hsd[4 * k4 + 3] * wv.w;
        }
        size_t o = (size_t)rowid * NCLS + tid;
        if (sizeof(T) == 2) ((u16*)out)[o] = f2b(acc);
        else                ((float*)out)[o] = acc;
    }
}
__global__ __launch_bounds__(64) void gen_kernel(
    const u16* hs, const void* gen_w, const void* gen_b, void* out, const int* flagp)
{
    if (*flagp) gen_body(hs, (const u16*)gen_w, (const u16*)gen_b, out);
    else        gen_body(hs, (const float*)gen_w, (const float*)gen_b, out);
}

extern "C" void kernel_launch(void* const* d_in, const int* in_sizes, int n_in,
                              void* d_out, int out_size, void* d_ws, size_t ws_size,
                              hipStream_t stream) {
    (void)in_sizes; (void)n_in; (void)out_size;
    const int* text = (const int*)d_in[6];

    char* ws = (char*)d_ws;
    size_t off = 256;
    int* flag = (int*)ws;
    u16* fp = (u16*)(ws + off); off += (size_t)NB * NT * HID * 2;        // 16.78 MB
    u16* ft = (u16*)(ws + off); off += (size_t)NB * NC * NT * 2;         // 33.55 MB
    u16* hs     = (u16*)(ws + off); off += 3407872;
    u16* x      = (u16*)(ws + off); off += 753664;
    u16* wih_c  = (u16*)(ws + off); off += 2260992;
    u16* whh_c  = (u16*)(ws + off); off += 393216;
    u16* h2h_wT = (u16*)(ws + off); off += 131072;
    u16* pt     = (u16*)(ws + off); off += (size_t)NB * POSEC * NT * 2;  // 16.78 MB

    probe_kernel<<<1, 128, 0, stream>>>(d_in[10], flag);
    conv_kernel<<<512, 256, 0, stream>>>(d_in[13], d_in[14], d_in[8],
                                         wih_c, whh_c, h2h_wT, flag);
    hipMemsetAsync(hs, 0, (size_t)NB * HID * 2, stream);  // h0 = 0
    fp_kernel<<<256, 512, 0, stream>>>(d_in[0], d_in[7], fp, flag);
    trans_kernel<<<dim3(NB, NT / 8), 256, 0, stream>>>(d_in[0], ft, flag);
    pconv_kernel<<<2048, 256, 0, stream>>>(d_in[1], pt, flag);

    for (int s = 0; s < NSTEPS; s++) {
        attn_kernel<<<NB, 512, 0, stream>>>(
            pt, d_in[2], d_in[3], d_in[4], text,
            d_in[9], d_in[10], d_in[11], d_in[12], d_in[17],
            h2h_wT, ft, fp, hs + (size_t)s * NB * HID, x, s, flag);
        gru_kernel<<<dim3(16, 16), 512, 34816, stream>>>(
            x, hs + (size_t)s * NB * HID, hs + (size_t)(s + 1) * NB * HID,
            wih_c, whh_c, d_in[15], d_in[16], flag);
    }
    gen_kernel<<<NB * NSTEPS, 64, 1024, stream>>>(hs, d_in[18], d_in[19], d_out, flag);
}